// Round 4
// baseline (471.056 us; speedup 1.0000x reference)
//
#include <hip/hip_runtime.h>
#include <hip/hip_bf16.h>
#include <math.h>

#define H_DIM 2048
#define I_DIM 768
#define NEXP  8
#define TTOK  2048

typedef __bf16 bf16x8 __attribute__((ext_vector_type(8)));
typedef __bf16 bf16x4 __attribute__((ext_vector_type(4)));
typedef float  f32x4  __attribute__((ext_vector_type(4)));

// ---- workspace layout (bytes) ----
#define WS_COUNTS   0u
#define WS_TOK      128u          // NEXP*TTOK int    (65536)
#define WS_WGTW     65664u        // NEXP*TTOK float  (65536)
#define WS_XBF      131328u       // TTOK*H_DIM bf16  (8388608)
#define WS_HBUF     8519936u      // (4096+128)*I_DIM bf16 (6488064)
#define WS_WG_T     15008000u     // 8*768*2048 bf16  (25165824)
#define WS_WU_T     40173824u     // 8*768*2048 bf16  (25165824)
#define WS_WD_T     65339648u     // 8*2048*768 bf16  (25165824)
// end: 90505472 (~86.3 MB)

// async global->LDS, 16B per lane; LDS dest is wave-uniform base + lane*16
__device__ __forceinline__ void gl2l(const __bf16* g, __bf16* l) {
    __builtin_amdgcn_global_load_lds(
        (const __attribute__((address_space(1))) unsigned int*)g,
        (__attribute__((address_space(3))) unsigned int*)l, 16, 0, 0);
}

// ---------------- x fp32 -> bf16 ----------------
__global__ void xconv_k(const float* __restrict__ x, __bf16* __restrict__ xb) {
    int i = (blockIdx.x * 256 + threadIdx.x) * 4;
    float4 v = *(const float4*)(x + i);
    bf16x4 o;
    o[0] = (__bf16)v.x; o[1] = (__bf16)v.y; o[2] = (__bf16)v.z; o[3] = (__bf16)v.w;
    *(bf16x4*)(xb + i) = o;
}

// ---------------- weight transpose+convert: [E][K][N] fp32 -> [E][N][K] bf16 ----------------
__global__ __launch_bounds__(256) void wtrans_k(const float* __restrict__ in0,
                                                const float* __restrict__ in1,
                                                __bf16* __restrict__ out0,
                                                __bf16* __restrict__ out1,
                                                int K, int N) {
    const int z = blockIdx.z;
    const int e = z & 7;
    const float* in  = (z >> 3) ? in1  : in0;
    __bf16*     out  = (z >> 3) ? out1 : out0;
    const int k0 = blockIdx.x * 64, n0 = blockIdx.y * 64;
    __shared__ float sT[64 * 65];
    const float* ip = in + (size_t)e * K * N;
    const int t = threadIdx.x;
    const int kl = t >> 4;            // 0..15
    const int n4 = (t & 15) * 4;
#pragma unroll
    for (int j = 0; j < 4; ++j) {
        int k = kl + j * 16;
        float4 v = *(const float4*)(ip + (size_t)(k0 + k) * N + n0 + n4);
        sT[(n4 + 0) * 65 + k] = v.x;
        sT[(n4 + 1) * 65 + k] = v.y;
        sT[(n4 + 2) * 65 + k] = v.z;
        sT[(n4 + 3) * 65 + k] = v.w;
    }
    __syncthreads();
    const int n = t >> 2;             // 0..63
    const int kc = (t & 3) * 16;
    bf16x8 o0, o1;
#pragma unroll
    for (int j = 0; j < 8; ++j) {
        o0[j] = (__bf16)sT[n * 65 + kc + j];
        o1[j] = (__bf16)sT[n * 65 + kc + 8 + j];
    }
    __bf16* op = out + (size_t)e * N * K + (size_t)(n0 + n) * K + k0 + kc;
    *(bf16x8*)op = o0;
    *(bf16x8*)(op + 8) = o1;
}

// ---------------- router ----------------
__global__ __launch_bounds__(256) void router_k(const float* __restrict__ x,
                                                const float* __restrict__ wgate,
                                                int* __restrict__ counts,
                                                int* __restrict__ tok_list,
                                                float* __restrict__ wgt) {
    const int t = blockIdx.x;
    const int tid = threadIdx.x;
    float acc[NEXP];
#pragma unroll
    for (int e = 0; e < NEXP; ++e) acc[e] = 0.f;
    const float* xr = x + (size_t)t * H_DIM;
    for (int k = tid; k < H_DIM; k += 256) {
        float xv = xr[k];
#pragma unroll
        for (int e = 0; e < NEXP; ++e) acc[e] += xv * wgate[e * H_DIM + k];
    }
    __shared__ float s_red[NEXP][4];
    __shared__ float s_logit[NEXP];
    const int lane = tid & 63, w = tid >> 6;
#pragma unroll
    for (int e = 0; e < NEXP; ++e) {
        float v = acc[e];
#pragma unroll
        for (int off = 32; off > 0; off >>= 1) v += __shfl_down(v, off, 64);
        if (lane == 0) s_red[e][w] = v;
    }
    __syncthreads();
    if (tid < NEXP) s_logit[tid] = s_red[tid][0] + s_red[tid][1] + s_red[tid][2] + s_red[tid][3];
    __syncthreads();
    if (tid == 0) {
        int i0 = 0; float l0 = s_logit[0];
        for (int e = 1; e < NEXP; ++e) if (s_logit[e] > l0) { l0 = s_logit[e]; i0 = e; }
        int i1 = -1; float l1 = -1e30f;
        for (int e = 0; e < NEXP; ++e) if (e != i0 && s_logit[e] > l1) { l1 = s_logit[e]; i1 = e; }
        float w0 = 1.f / (1.f + expf(l1 - l0));
        float w1 = 1.f - w0;
        int p0 = atomicAdd(&counts[i0], 1);
        tok_list[i0 * TTOK + p0] = t; wgt[i0 * TTOK + p0] = w0;
        int p1 = atomicAdd(&counts[i1], 1);
        tok_list[i1 * TTOK + p1] = t; wgt[i1 * TTOK + p1] = w1;
    }
}

// ---------------- GEMM1: h = silu(x@Wg)*(x@Wu); BM=64, BN=64(G)+64(U), BK=64, double-buffered ----------------
__global__ __launch_bounds__(256, 3) void gemm1_k(
    const __bf16* __restrict__ xb, const __bf16* __restrict__ Wgt,
    const __bf16* __restrict__ Wut, const int* __restrict__ counts,
    const int* __restrict__ tok_list, __bf16* __restrict__ hbuf) {
    const int e = blockIdx.z;
    const int cnt = counts[e];
    const int m0 = blockIdx.x * 64;
    if (m0 >= cnt) return;
    const int nt = blockIdx.y;      // 0..11
    const int tid = threadIdx.x;
    const int lane = tid & 63, w = tid >> 6;

    __shared__ __bf16 sA[2][64 * 64];
    __shared__ __bf16 sG[2][64 * 64];
    __shared__ __bf16 sU[2][64 * 64];
    __shared__ int s_tok[64];
    __shared__ int s_off;

    if (tid == 0) { int o = 0; for (int j = 0; j < e; ++j) o += counts[j]; s_off = o; }
    if (tid < 64) {
        int m = m0 + tid;
        s_tok[tid] = tok_list[e * TTOK + (m < cnt ? m : cnt - 1)];
    }
    __syncthreads();
    const int off = s_off;

    // staging: per wave-issue 8 rows x 64k; logical chunk c of row r stored at slot c^(r&7)
    const int lr = lane >> 3;
    const int gofs = ((lane & 7) ^ lr) * 8;
    const __bf16* pA[2]; const __bf16* pG[2]; const __bf16* pU[2];
    int lofs[2];
#pragma unroll
    for (int i = 0; i < 2; ++i) {
        int r = w * 8 + i * 32 + lr;
        pA[i] = xb + (size_t)s_tok[r] * H_DIM + gofs;
        size_t grow = (size_t)e * I_DIM + nt * 64 + r;
        pG[i] = Wgt + grow * H_DIM + gofs;
        pU[i] = Wut + grow * H_DIM + gofs;
        lofs[i] = (w * 8 + i * 32) * 64;
    }

    const int wm = w & 1, wn = w >> 1;
    const int l15 = lane & 15, l7 = lane & 7, kq = lane >> 4;
    int swzk[2];
    swzk[0] = (kq ^ l7) * 8;
    swzk[1] = ((kq + 4) ^ l7) * 8;
    const int arow = wm * 32 + l15;

    f32x4 accG[2][2], accU[2][2];
#pragma unroll
    for (int mf = 0; mf < 2; ++mf)
#pragma unroll
        for (int nf = 0; nf < 2; ++nf) {
            accG[mf][nf] = (f32x4){0.f, 0.f, 0.f, 0.f};
            accU[mf][nf] = (f32x4){0.f, 0.f, 0.f, 0.f};
        }

    // prefetch tile 0 into buf 0
#pragma unroll
    for (int i = 0; i < 2; ++i) {
        gl2l(pA[i], &sA[0][lofs[i]]);
        gl2l(pG[i], &sG[0][lofs[i]]);
        gl2l(pU[i], &sU[0][lofs[i]]);
    }

#pragma unroll 2
    for (int it = 0; it < 32; ++it) {
        const int p = it & 1;
        __syncthreads();            // drains prefetch of tile `it`; syncs reuse of buf p
        if (it + 1 < 32) {
            const int kn = (it + 1) * 64;
#pragma unroll
            for (int i = 0; i < 2; ++i) {
                gl2l(pA[i] + kn, &sA[p ^ 1][lofs[i]]);
                gl2l(pG[i] + kn, &sG[p ^ 1][lofs[i]]);
                gl2l(pU[i] + kn, &sU[p ^ 1][lofs[i]]);
            }
        }
#pragma unroll
        for (int ch = 0; ch < 2; ++ch) {
            bf16x8 af[2], bg[2], bu[2];
#pragma unroll
            for (int mf = 0; mf < 2; ++mf)
                af[mf] = *(const bf16x8*)(&sA[p][0] + (arow + mf * 16) * 64 + swzk[ch]);
#pragma unroll
            for (int nf = 0; nf < 2; ++nf) {
                int br = wn * 32 + nf * 16 + l15;
                bg[nf] = *(const bf16x8*)(&sG[p][0] + br * 64 + swzk[ch]);
                bu[nf] = *(const bf16x8*)(&sU[p][0] + br * 64 + swzk[ch]);
            }
#pragma unroll
            for (int mf = 0; mf < 2; ++mf)
#pragma unroll
                for (int nf = 0; nf < 2; ++nf) {
                    accG[mf][nf] = __builtin_amdgcn_mfma_f32_16x16x32_bf16(af[mf], bg[nf], accG[mf][nf], 0, 0, 0);
                    accU[mf][nf] = __builtin_amdgcn_mfma_f32_16x16x32_bf16(af[mf], bu[nf], accU[mf][nf], 0, 0, 0);
                }
        }
    }

    // epilogue: silu(g)*u -> bf16 (C layout: col=lane&15, row=(lane>>4)*4+reg)
#pragma unroll
    for (int mf = 0; mf < 2; ++mf) {
#pragma unroll
        for (int reg = 0; reg < 4; ++reg) {
            int m = m0 + wm * 32 + mf * 16 + kq * 4 + reg;
            if (m < cnt) {
                size_t rowbase = (size_t)(off + m) * I_DIM;
#pragma unroll
                for (int nf = 0; nf < 2; ++nf) {
                    float g = accG[mf][nf][reg], u = accU[mf][nf][reg];
                    float h = (g / (1.f + __expf(-g))) * u;
                    hbuf[rowbase + nt * 64 + wn * 32 + nf * 16 + l15] = (__bf16)h;
                }
            }
        }
    }
}

// ---------------- GEMM2: y = h @ Wd_t, scatter-add w*y; BM=64, BN=128, BK=64, double-buffered ----------------
__global__ __launch_bounds__(256, 3) void gemm2_k(
    const __bf16* __restrict__ hbuf, const __bf16* __restrict__ Wdt,
    const int* __restrict__ counts, const int* __restrict__ tok_list,
    const float* __restrict__ wgt, float* __restrict__ out) {
    const int e = blockIdx.z;
    const int cnt = counts[e];
    const int m0 = blockIdx.x * 64;
    if (m0 >= cnt) return;
    const int nt = blockIdx.y;    // 0..15
    const int tid = threadIdx.x;
    const int lane = tid & 63, w = tid >> 6;

    __shared__ __bf16 sA[2][64 * 64];
    __shared__ __bf16 sB[2][128 * 64];
    __shared__ int s_tok[64];
    __shared__ float s_w[64];
    __shared__ int s_off;

    if (tid == 0) { int o = 0; for (int j = 0; j < e; ++j) o += counts[j]; s_off = o; }
    if (tid < 64) {
        int m = m0 + tid;
        if (m < cnt) { s_tok[tid] = tok_list[e * TTOK + m]; s_w[tid] = wgt[e * TTOK + m]; }
        else         { s_tok[tid] = 0;                      s_w[tid] = 0.f; }
    }
    __syncthreads();
    const int off = s_off;

    const int lr = lane >> 3;
    const int gofs = ((lane & 7) ^ lr) * 8;
    const __bf16* pA[2]; int lofsA[2];
    const __bf16* pB[4]; int lofsB[4];
#pragma unroll
    for (int i = 0; i < 2; ++i) {
        int r = w * 8 + i * 32 + lr;
        pA[i] = hbuf + (size_t)(off + m0 + r) * I_DIM + gofs;
        lofsA[i] = (w * 8 + i * 32) * 64;
    }
#pragma unroll
    for (int i = 0; i < 4; ++i) {
        int r = w * 8 + i * 32 + lr;
        pB[i] = Wdt + ((size_t)e * H_DIM + nt * 128 + r) * I_DIM + gofs;
        lofsB[i] = (w * 8 + i * 32) * 64;
    }

    const int wm = w & 1, wn = w >> 1;
    const int l15 = lane & 15, l7 = lane & 7, kq = lane >> 4;
    int swzk[2];
    swzk[0] = (kq ^ l7) * 8;
    swzk[1] = ((kq + 4) ^ l7) * 8;
    const int arow = wm * 32 + l15;

    f32x4 acc[2][4];
#pragma unroll
    for (int mf = 0; mf < 2; ++mf)
#pragma unroll
        for (int nf = 0; nf < 4; ++nf) acc[mf][nf] = (f32x4){0.f, 0.f, 0.f, 0.f};

#pragma unroll
    for (int i = 0; i < 2; ++i) gl2l(pA[i], &sA[0][lofsA[i]]);
#pragma unroll
    for (int i = 0; i < 4; ++i) gl2l(pB[i], &sB[0][lofsB[i]]);

#pragma unroll 2
    for (int it = 0; it < 12; ++it) {
        const int p = it & 1;
        __syncthreads();
        if (it + 1 < 12) {
            const int kn = (it + 1) * 64;
#pragma unroll
            for (int i = 0; i < 2; ++i) gl2l(pA[i] + kn, &sA[p ^ 1][lofsA[i]]);
#pragma unroll
            for (int i = 0; i < 4; ++i) gl2l(pB[i] + kn, &sB[p ^ 1][lofsB[i]]);
        }
#pragma unroll
        for (int ch = 0; ch < 2; ++ch) {
            bf16x8 af[2], bb[4];
#pragma unroll
            for (int mf = 0; mf < 2; ++mf)
                af[mf] = *(const bf16x8*)(&sA[p][0] + (arow + mf * 16) * 64 + swzk[ch]);
#pragma unroll
            for (int nf = 0; nf < 4; ++nf)
                bb[nf] = *(const bf16x8*)(&sB[p][0] + (wn * 64 + nf * 16 + l15) * 64 + swzk[ch]);
#pragma unroll
            for (int mf = 0; mf < 2; ++mf)
#pragma unroll
                for (int nf = 0; nf < 4; ++nf)
                    acc[mf][nf] = __builtin_amdgcn_mfma_f32_16x16x32_bf16(af[mf], bb[nf], acc[mf][nf], 0, 0, 0);
        }
    }

#pragma unroll
    for (int mf = 0; mf < 2; ++mf) {
#pragma unroll
        for (int reg = 0; reg < 4; ++reg) {
            int m_loc = wm * 32 + mf * 16 + kq * 4 + reg;
            if (m0 + m_loc < cnt) {
                int tok = s_tok[m_loc];
                float wv = s_w[m_loc];
                float* orow = out + (size_t)tok * H_DIM + nt * 128 + wn * 64 + l15;
#pragma unroll
                for (int nf = 0; nf < 4; ++nf)
                    atomicAdd(orow + nf * 16, wv * acc[mf][nf][reg]);
            }
        }
    }
}

extern "C" void kernel_launch(void* const* d_in, const int* in_sizes, int n_in,
                              void* d_out, int out_size, void* d_ws, size_t ws_size,
                              hipStream_t stream) {
    const float* x     = (const float*)d_in[0];
    const float* Wgate = (const float*)d_in[1];
    const float* Wg    = (const float*)d_in[2];
    const float* Wu    = (const float*)d_in[3];
    const float* Wd    = (const float*)d_in[4];
    float* out = (float*)d_out;
    char* ws = (char*)d_ws;

    int*    counts   = (int*)(ws + WS_COUNTS);
    int*    tok_list = (int*)(ws + WS_TOK);
    float*  wgt      = (float*)(ws + WS_WGTW);
    __bf16* xb       = (__bf16*)(ws + WS_XBF);
    __bf16* hbuf     = (__bf16*)(ws + WS_HBUF);
    __bf16* Wg_t     = (__bf16*)(ws + WS_WG_T);
    __bf16* Wu_t     = (__bf16*)(ws + WS_WU_T);
    __bf16* Wd_t     = (__bf16*)(ws + WS_WD_T);

    hipMemsetAsync(counts, 0, 32, stream);
    hipMemsetAsync(d_out, 0, (size_t)TTOK * H_DIM * sizeof(float), stream);

    xconv_k<<<(TTOK * H_DIM / 4) / 256, 256, 0, stream>>>(x, xb);
    router_k<<<TTOK, 256, 0, stream>>>(x, Wgate, counts, tok_list, wgt);
    // Wg,Wu: [E][2048][768] -> [E][768][2048] ; Wd: [E][768][2048] -> [E][2048][768]
    wtrans_k<<<dim3(H_DIM / 64, I_DIM / 64, 2 * NEXP), 256, 0, stream>>>(Wg, Wu, Wg_t, Wu_t, H_DIM, I_DIM);
    wtrans_k<<<dim3(I_DIM / 64, H_DIM / 64, NEXP), 256, 0, stream>>>(Wd, Wd, Wd_t, Wd_t, I_DIM, H_DIM);
    gemm1_k<<<dim3(32, I_DIM / 64, NEXP), 256, 0, stream>>>(xb, Wg_t, Wu_t, counts, tok_list, hbuf);
    gemm2_k<<<dim3(32, H_DIM / 128, NEXP), 256, 0, stream>>>(hbuf, Wd_t, counts, tok_list, wgt, out);
}

// Round 5
// 368.630 us; speedup vs baseline: 1.2779x; 1.2779x over previous
//
#include <hip/hip_runtime.h>
#include <hip/hip_bf16.h>
#include <math.h>

#define H_DIM 2048
#define I_DIM 768
#define NEXP  8
#define TTOK  2048

typedef __bf16 bf16x8 __attribute__((ext_vector_type(8)));
typedef __bf16 bf16x4 __attribute__((ext_vector_type(4)));
typedef float  f32x4  __attribute__((ext_vector_type(4)));

// ---- workspace layout (bytes) ----
#define WS_COUNTS   0u
#define WS_TOK      128u          // NEXP*TTOK int    (65536)
#define WS_WGTW     65664u        // NEXP*TTOK float  (65536)
#define WS_XBF      131328u       // TTOK*H_DIM bf16  (8388608)
#define WS_HBUF     8519936u      // (4096+128)*I_DIM bf16 (6488064)
#define WS_WG_T     15008000u     // 8*768*2048 bf16  (25165824)
#define WS_WU_T     40173824u     // 8*768*2048 bf16  (25165824)
#define WS_WD_T     65339648u     // 8*2048*768 bf16  (25165824)
// end: 90505472 (~86.3 MB)

// async global->LDS, 16B per lane; LDS dest is wave-uniform base + lane*16
__device__ __forceinline__ void gl2l(const __bf16* g, __bf16* l) {
    __builtin_amdgcn_global_load_lds(
        (const __attribute__((address_space(1))) unsigned int*)g,
        (__attribute__((address_space(3))) unsigned int*)l, 16, 0, 0);
}

// pipeline sync: wait for all but the newest 6 vector loads, then raw barrier.
// (NOT __syncthreads(): that drains vmcnt(0) and kills the prefetch pipeline.)
__device__ __forceinline__ void pipe_sync_vm6() {
    asm volatile("" ::: "memory");
    __builtin_amdgcn_s_waitcnt(0xF76);   // vmcnt(6), lgkmcnt/expcnt don't-care
    __builtin_amdgcn_s_barrier();
    asm volatile("" ::: "memory");
}
__device__ __forceinline__ void pipe_sync_vm0() {
    asm volatile("" ::: "memory");
    __builtin_amdgcn_s_waitcnt(0xF70);   // vmcnt(0)
    __builtin_amdgcn_s_barrier();
    asm volatile("" ::: "memory");
}

// ---------------- x fp32 -> bf16 ----------------
__global__ void xconv_k(const float* __restrict__ x, __bf16* __restrict__ xb) {
    int i = (blockIdx.x * 256 + threadIdx.x) * 4;
    float4 v = *(const float4*)(x + i);
    bf16x4 o;
    o[0] = (__bf16)v.x; o[1] = (__bf16)v.y; o[2] = (__bf16)v.z; o[3] = (__bf16)v.w;
    *(bf16x4*)(xb + i) = o;
}

// ---------------- weight transpose+convert: [E][K][N] fp32 -> [E][N][K] bf16 ----------------
__global__ __launch_bounds__(256) void wtrans_k(const float* __restrict__ in0,
                                                const float* __restrict__ in1,
                                                __bf16* __restrict__ out0,
                                                __bf16* __restrict__ out1,
                                                int K, int N) {
    const int z = blockIdx.z;
    const int e = z & 7;
    const float* in  = (z >> 3) ? in1  : in0;
    __bf16*     out  = (z >> 3) ? out1 : out0;
    const int k0 = blockIdx.x * 64, n0 = blockIdx.y * 64;
    __shared__ float sT[64 * 65];
    const float* ip = in + (size_t)e * K * N;
    const int t = threadIdx.x;
    const int kl = t >> 4;            // 0..15
    const int n4 = (t & 15) * 4;
#pragma unroll
    for (int j = 0; j < 4; ++j) {
        int k = kl + j * 16;
        float4 v = *(const float4*)(ip + (size_t)(k0 + k) * N + n0 + n4);
        sT[(n4 + 0) * 65 + k] = v.x;
        sT[(n4 + 1) * 65 + k] = v.y;
        sT[(n4 + 2) * 65 + k] = v.z;
        sT[(n4 + 3) * 65 + k] = v.w;
    }
    __syncthreads();
    const int n = t >> 2;             // 0..63
    const int kc = (t & 3) * 16;
    bf16x8 o0, o1;
#pragma unroll
    for (int j = 0; j < 8; ++j) {
        o0[j] = (__bf16)sT[n * 65 + kc + j];
        o1[j] = (__bf16)sT[n * 65 + kc + 8 + j];
    }
    __bf16* op = out + (size_t)e * N * K + (size_t)(n0 + n) * K + k0 + kc;
    *(bf16x8*)op = o0;
    *(bf16x8*)(op + 8) = o1;
}

// ---------------- router ----------------
__global__ __launch_bounds__(256) void router_k(const float* __restrict__ x,
                                                const float* __restrict__ wgate,
                                                int* __restrict__ counts,
                                                int* __restrict__ tok_list,
                                                float* __restrict__ wgt) {
    const int t = blockIdx.x;
    const int tid = threadIdx.x;
    float acc[NEXP];
#pragma unroll
    for (int e = 0; e < NEXP; ++e) acc[e] = 0.f;
    const float* xr = x + (size_t)t * H_DIM;
    for (int k = tid; k < H_DIM; k += 256) {
        float xv = xr[k];
#pragma unroll
        for (int e = 0; e < NEXP; ++e) acc[e] += xv * wgate[e * H_DIM + k];
    }
    __shared__ float s_red[NEXP][4];
    __shared__ float s_logit[NEXP];
    const int lane = tid & 63, w = tid >> 6;
#pragma unroll
    for (int e = 0; e < NEXP; ++e) {
        float v = acc[e];
#pragma unroll
        for (int off = 32; off > 0; off >>= 1) v += __shfl_down(v, off, 64);
        if (lane == 0) s_red[e][w] = v;
    }
    __syncthreads();
    if (tid < NEXP) s_logit[tid] = s_red[tid][0] + s_red[tid][1] + s_red[tid][2] + s_red[tid][3];
    __syncthreads();
    if (tid == 0) {
        int i0 = 0; float l0 = s_logit[0];
        for (int e = 1; e < NEXP; ++e) if (s_logit[e] > l0) { l0 = s_logit[e]; i0 = e; }
        int i1 = -1; float l1 = -1e30f;
        for (int e = 0; e < NEXP; ++e) if (e != i0 && s_logit[e] > l1) { l1 = s_logit[e]; i1 = e; }
        float w0 = 1.f / (1.f + expf(l1 - l0));
        float w1 = 1.f - w0;
        int p0 = atomicAdd(&counts[i0], 1);
        tok_list[i0 * TTOK + p0] = t; wgt[i0 * TTOK + p0] = w0;
        int p1 = atomicAdd(&counts[i1], 1);
        tok_list[i1 * TTOK + p1] = t; wgt[i1 * TTOK + p1] = w1;
    }
}

// ---------------- GEMM1: h = silu(x@Wg)*(x@Wu); BM=64, BN=64(G)+64(U), BK=64 ----------------
// 3-stage pipeline (prefetch depth 2) with raw s_barrier + vmcnt(6): loads stay in flight
// across barriers. Grid: x = e*12+nt (96), y = m-tile; same weight stripe -> same XCD (stride 96%8==0).
__global__ __launch_bounds__(256, 2) void gemm1_k(
    const __bf16* __restrict__ xb, const __bf16* __restrict__ Wgt,
    const __bf16* __restrict__ Wut, const int* __restrict__ counts,
    const int* __restrict__ tok_list, __bf16* __restrict__ hbuf) {
    const int g = blockIdx.x;
    const int e = g / 12, nt = g % 12;
    const int cnt = counts[e];
    const int m0 = blockIdx.y * 64;
    if (m0 >= cnt) return;
    const int tid = threadIdx.x;
    const int lane = tid & 63, w = tid >> 6;

    __shared__ __bf16 sA[3][64 * 64];
    __shared__ __bf16 sG[3][64 * 64];
    __shared__ __bf16 sU[3][64 * 64];
    __shared__ int s_tok[64];
    __shared__ int s_off;

    if (tid == 0) { int o = 0; for (int j = 0; j < e; ++j) o += counts[j]; s_off = o; }
    if (tid < 64) {
        int m = m0 + tid;
        s_tok[tid] = tok_list[e * TTOK + (m < cnt ? m : cnt - 1)];
    }
    __syncthreads();          // full drain once, before the pipeline starts
    const int off = s_off;

    // staging: per wave-issue 8 rows x 64k; logical chunk c of row r stored at slot c^(r&7)
    const int lr = lane >> 3;
    const int gofs = ((lane & 7) ^ lr) * 8;
    const __bf16* pA[2]; const __bf16* pG[2]; const __bf16* pU[2];
    int lofs[2];
#pragma unroll
    for (int i = 0; i < 2; ++i) {
        int r = w * 8 + i * 32 + lr;
        pA[i] = xb + (size_t)s_tok[r] * H_DIM + gofs;
        size_t grow = (size_t)e * I_DIM + nt * 64 + r;
        pG[i] = Wgt + grow * H_DIM + gofs;
        pU[i] = Wut + grow * H_DIM + gofs;
        lofs[i] = (w * 8 + i * 32) * 64;
    }

    const int wm = w & 1, wn = w >> 1;
    const int l15 = lane & 15, l7 = lane & 7, kq = lane >> 4;
    int swzk[2];
    swzk[0] = (kq ^ l7) * 8;
    swzk[1] = ((kq + 4) ^ l7) * 8;
    const int arow = wm * 32 + l15;

    f32x4 accG[2][2], accU[2][2];
#pragma unroll
    for (int mf = 0; mf < 2; ++mf)
#pragma unroll
        for (int nf = 0; nf < 2; ++nf) {
            accG[mf][nf] = (f32x4){0.f, 0.f, 0.f, 0.f};
            accU[mf][nf] = (f32x4){0.f, 0.f, 0.f, 0.f};
        }

    // issue tiles 0 and 1 (6 gl2l per wave per tile)
#pragma unroll
    for (int t0 = 0; t0 < 2; ++t0) {
        const int kb = t0 * 64;
#pragma unroll
        for (int i = 0; i < 2; ++i) {
            gl2l(pA[i] + kb, &sA[t0][lofs[i]]);
            gl2l(pG[i] + kb, &sG[t0][lofs[i]]);
            gl2l(pU[i] + kb, &sU[t0][lofs[i]]);
        }
    }

#define G1_COMPUTE(P)                                                                   \
    {                                                                                   \
        _Pragma("unroll")                                                               \
        for (int ch = 0; ch < 2; ++ch) {                                                \
            bf16x8 af[2], bg[2], bu[2];                                                 \
            _Pragma("unroll")                                                           \
            for (int mf = 0; mf < 2; ++mf)                                              \
                af[mf] = *(const bf16x8*)(&sA[P][0] + (arow + mf * 16) * 64 + swzk[ch]);\
            _Pragma("unroll")                                                           \
            for (int nf = 0; nf < 2; ++nf) {                                            \
                int br = wn * 32 + nf * 16 + l15;                                       \
                bg[nf] = *(const bf16x8*)(&sG[P][0] + br * 64 + swzk[ch]);              \
                bu[nf] = *(const bf16x8*)(&sU[P][0] + br * 64 + swzk[ch]);              \
            }                                                                           \
            _Pragma("unroll")                                                           \
            for (int mf = 0; mf < 2; ++mf)                                              \
                _Pragma("unroll")                                                       \
                for (int nf = 0; nf < 2; ++nf) {                                        \
                    accG[mf][nf] = __builtin_amdgcn_mfma_f32_16x16x32_bf16(af[mf], bg[nf], accG[mf][nf], 0, 0, 0); \
                    accU[mf][nf] = __builtin_amdgcn_mfma_f32_16x16x32_bf16(af[mf], bu[nf], accU[mf][nf], 0, 0, 0); \
                }                                                                       \
        }                                                                               \
    }

    // steady state: iters 0..29 (issue tile it+2, uniform body; unroll 3 keeps buffer idx constant)
#pragma unroll 3
    for (int it = 0; it < 30; ++it) {
        const int p = it % 3;
        const int pn = (it + 2) % 3;
        pipe_sync_vm6();            // tile it landed (tile it+1's 6 loads still in flight)
        const int kn = (it + 2) * 64;
#pragma unroll
        for (int i = 0; i < 2; ++i) {
            gl2l(pA[i] + kn, &sA[pn][lofs[i]]);
            gl2l(pG[i] + kn, &sG[pn][lofs[i]]);
            gl2l(pU[i] + kn, &sU[pn][lofs[i]]);
        }
        G1_COMPUTE(p);
    }
    // tail: tile 30 (tile 31 in flight), then tile 31
    pipe_sync_vm6();
    G1_COMPUTE(0);                  // 30 % 3 == 0
    pipe_sync_vm0();
    G1_COMPUTE(1);                  // 31 % 3 == 1
#undef G1_COMPUTE

    // epilogue: silu(g)*u -> bf16 (C layout: col=lane&15, row=(lane>>4)*4+reg)
#pragma unroll
    for (int mf = 0; mf < 2; ++mf) {
#pragma unroll
        for (int reg = 0; reg < 4; ++reg) {
            int m = m0 + wm * 32 + mf * 16 + kq * 4 + reg;
            if (m < cnt) {
                size_t rowbase = (size_t)(off + m) * I_DIM;
#pragma unroll
                for (int nf = 0; nf < 2; ++nf) {
                    float g1 = accG[mf][nf][reg], u1 = accU[mf][nf][reg];
                    float h = (g1 / (1.f + __expf(-g1))) * u1;
                    hbuf[rowbase + nt * 64 + wn * 32 + nf * 16 + l15] = (__bf16)h;
                }
            }
        }
    }
}

// ---------------- GEMM2: y = h @ Wd_t, scatter-add w*y; BM=64, BN=128, BK=64 ----------------
// same 3-stage raw-barrier pipeline; grid x = e*16+nt (128), y = m-tile (stride 128%8==0).
__global__ __launch_bounds__(256, 2) void gemm2_k(
    const __bf16* __restrict__ hbuf, const __bf16* __restrict__ Wdt,
    const int* __restrict__ counts, const int* __restrict__ tok_list,
    const float* __restrict__ wgt, float* __restrict__ out) {
    const int g = blockIdx.x;
    const int e = g >> 4, nt = g & 15;
    const int cnt = counts[e];
    const int m0 = blockIdx.y * 64;
    if (m0 >= cnt) return;
    const int tid = threadIdx.x;
    const int lane = tid & 63, w = tid >> 6;

    __shared__ __bf16 sA[3][64 * 64];
    __shared__ __bf16 sB[3][128 * 64];
    __shared__ int s_tok[64];
    __shared__ float s_w[64];
    __shared__ int s_off;

    if (tid == 0) { int o = 0; for (int j = 0; j < e; ++j) o += counts[j]; s_off = o; }
    if (tid < 64) {
        int m = m0 + tid;
        if (m < cnt) { s_tok[tid] = tok_list[e * TTOK + m]; s_w[tid] = wgt[e * TTOK + m]; }
        else         { s_tok[tid] = 0;                      s_w[tid] = 0.f; }
    }
    __syncthreads();
    const int off = s_off;

    const int lr = lane >> 3;
    const int gofs = ((lane & 7) ^ lr) * 8;
    const __bf16* pA[2]; int lofsA[2];
    const __bf16* pB[4]; int lofsB[4];
#pragma unroll
    for (int i = 0; i < 2; ++i) {
        int r = w * 8 + i * 32 + lr;
        pA[i] = hbuf + (size_t)(off + m0 + r) * I_DIM + gofs;
        lofsA[i] = (w * 8 + i * 32) * 64;
    }
#pragma unroll
    for (int i = 0; i < 4; ++i) {
        int r = w * 8 + i * 32 + lr;
        pB[i] = Wdt + ((size_t)e * H_DIM + nt * 128 + r) * I_DIM + gofs;
        lofsB[i] = (w * 8 + i * 32) * 64;
    }

    const int wm = w & 1, wn = w >> 1;
    const int l15 = lane & 15, l7 = lane & 7, kq = lane >> 4;
    int swzk[2];
    swzk[0] = (kq ^ l7) * 8;
    swzk[1] = ((kq + 4) ^ l7) * 8;
    const int arow = wm * 32 + l15;

    f32x4 acc[2][4];
#pragma unroll
    for (int mf = 0; mf < 2; ++mf)
#pragma unroll
        for (int nf = 0; nf < 4; ++nf) acc[mf][nf] = (f32x4){0.f, 0.f, 0.f, 0.f};

    // issue tiles 0,1 (6 gl2l per wave per tile: 2 A + 4 B)
#pragma unroll
    for (int t0 = 0; t0 < 2; ++t0) {
        const int kb = t0 * 64;
#pragma unroll
        for (int i = 0; i < 2; ++i) gl2l(pA[i] + kb, &sA[t0][lofsA[i]]);
#pragma unroll
        for (int i = 0; i < 4; ++i) gl2l(pB[i] + kb, &sB[t0][lofsB[i]]);
    }

#define G2_COMPUTE(P)                                                                   \
    {                                                                                   \
        _Pragma("unroll")                                                               \
        for (int ch = 0; ch < 2; ++ch) {                                                \
            bf16x8 af[2], bb[4];                                                        \
            _Pragma("unroll")                                                           \
            for (int mf = 0; mf < 2; ++mf)                                              \
                af[mf] = *(const bf16x8*)(&sA[P][0] + (arow + mf * 16) * 64 + swzk[ch]);\
            _Pragma("unroll")                                                           \
            for (int nf = 0; nf < 4; ++nf)                                              \
                bb[nf] = *(const bf16x8*)(&sB[P][0] + (wn * 64 + nf * 16 + l15) * 64 + swzk[ch]); \
            _Pragma("unroll")                                                           \
            for (int mf = 0; mf < 2; ++mf)                                              \
                _Pragma("unroll")                                                       \
                for (int nf = 0; nf < 4; ++nf)                                          \
                    acc[mf][nf] = __builtin_amdgcn_mfma_f32_16x16x32_bf16(af[mf], bb[nf], acc[mf][nf], 0, 0, 0); \
        }                                                                               \
    }

    // steady state: iters 0..8 issue tile it+2 (tiles 2..10)
#pragma unroll 3
    for (int it = 0; it < 9; ++it) {
        const int p = it % 3;
        const int pn = (it + 2) % 3;
        pipe_sync_vm6();
        const int kn = (it + 2) * 64;
#pragma unroll
        for (int i = 0; i < 2; ++i) gl2l(pA[i] + kn, &sA[pn][lofsA[i]]);
#pragma unroll
        for (int i = 0; i < 4; ++i) gl2l(pB[i] + kn, &sB[pn][lofsB[i]]);
        G2_COMPUTE(p);
    }
    // it=9: issue tile 11, compute 9 (p=0)
    pipe_sync_vm6();
    {
        const int kn = 11 * 64;
#pragma unroll
        for (int i = 0; i < 2; ++i) gl2l(pA[i] + kn, &sA[2][lofsA[i]]);
#pragma unroll
        for (int i = 0; i < 4; ++i) gl2l(pB[i] + kn, &sB[2][lofsB[i]]);
    }
    G2_COMPUTE(0);
    // it=10 (p=1), tile 11 in flight
    pipe_sync_vm6();
    G2_COMPUTE(1);
    // it=11 (p=2)
    pipe_sync_vm0();
    G2_COMPUTE(2);
#undef G2_COMPUTE

#pragma unroll
    for (int mf = 0; mf < 2; ++mf) {
#pragma unroll
        for (int reg = 0; reg < 4; ++reg) {
            int m_loc = wm * 32 + mf * 16 + kq * 4 + reg;
            if (m0 + m_loc < cnt) {
                int tok = s_tok[m_loc];
                float wv = s_w[m_loc];
                float* orow = out + (size_t)tok * H_DIM + nt * 128 + wn * 64 + l15;
#pragma unroll
                for (int nf = 0; nf < 4; ++nf)
                    atomicAdd(orow + nf * 16, wv * acc[mf][nf][reg]);
            }
        }
    }
}

extern "C" void kernel_launch(void* const* d_in, const int* in_sizes, int n_in,
                              void* d_out, int out_size, void* d_ws, size_t ws_size,
                              hipStream_t stream) {
    const float* x     = (const float*)d_in[0];
    const float* Wgate = (const float*)d_in[1];
    const float* Wg    = (const float*)d_in[2];
    const float* Wu    = (const float*)d_in[3];
    const float* Wd    = (const float*)d_in[4];
    float* out = (float*)d_out;
    char* ws = (char*)d_ws;

    int*    counts   = (int*)(ws + WS_COUNTS);
    int*    tok_list = (int*)(ws + WS_TOK);
    float*  wgt      = (float*)(ws + WS_WGTW);
    __bf16* xb       = (__bf16*)(ws + WS_XBF);
    __bf16* hbuf     = (__bf16*)(ws + WS_HBUF);
    __bf16* Wg_t     = (__bf16*)(ws + WS_WG_T);
    __bf16* Wu_t     = (__bf16*)(ws + WS_WU_T);
    __bf16* Wd_t     = (__bf16*)(ws + WS_WD_T);

    hipMemsetAsync(counts, 0, 32, stream);
    hipMemsetAsync(d_out, 0, (size_t)TTOK * H_DIM * sizeof(float), stream);

    xconv_k<<<(TTOK * H_DIM / 4) / 256, 256, 0, stream>>>(x, xb);
    router_k<<<TTOK, 256, 0, stream>>>(x, Wgate, counts, tok_list, wgt);
    // Wg,Wu: [E][2048][768] -> [E][768][2048] ; Wd: [E][768][2048] -> [E][2048][768]
    wtrans_k<<<dim3(H_DIM / 64, I_DIM / 64, 2 * NEXP), 256, 0, stream>>>(Wg, Wu, Wg_t, Wu_t, H_DIM, I_DIM);
    wtrans_k<<<dim3(I_DIM / 64, H_DIM / 64, NEXP), 256, 0, stream>>>(Wd, Wd, Wd_t, Wd_t, I_DIM, H_DIM);
    gemm1_k<<<dim3(96, 32), 256, 0, stream>>>(xb, Wg_t, Wu_t, counts, tok_list, hbuf);
    gemm2_k<<<dim3(128, 32), 256, 0, stream>>>(hbuf, Wd_t, counts, tok_list, wgt, out);
}

// Round 6
// 361.612 us; speedup vs baseline: 1.3027x; 1.0194x over previous
//
#include <hip/hip_runtime.h>
#include <hip/hip_bf16.h>
#include <math.h>

#define H_DIM 2048
#define I_DIM 768
#define NEXP  8
#define TTOK  2048

typedef __bf16 bf16x8 __attribute__((ext_vector_type(8)));
typedef __bf16 bf16x4 __attribute__((ext_vector_type(4)));
typedef float  f32x4  __attribute__((ext_vector_type(4)));

// ---- workspace layout (bytes) ----
#define WS_COUNTS   0u
#define WS_TOK      128u          // NEXP*TTOK int    (65536)
#define WS_WGTW     65664u        // NEXP*TTOK float  (65536)
#define WS_XBF      131328u       // TTOK*H_DIM bf16  (8388608)
#define WS_HBUF     8519936u      // (4096+128)*I_DIM bf16 (6488064)
#define WS_WG_T     15008000u     // 8*768*2048 bf16  (25165824)
#define WS_WU_T     40173824u     // 8*768*2048 bf16  (25165824)
#define WS_WD_T     65339648u     // 8*2048*768 bf16  (25165824)
// end: 90505472 (~86.3 MB)

// async global->LDS, 16B per lane; LDS dest is wave-uniform base + lane*16
__device__ __forceinline__ void gl2l(const __bf16* g, __bf16* l) {
    __builtin_amdgcn_global_load_lds(
        (const __attribute__((address_space(1))) unsigned int*)g,
        (__attribute__((address_space(3))) unsigned int*)l, 16, 0, 0);
}

// pipeline sync: wait until only N vector loads outstanding, then raw barrier.
// gfx9 waitcnt encoding: vmcnt[3:0], expcnt[6:4]=7 (ignore), lgkmcnt[11:8]=0xF (ignore)
__device__ __forceinline__ void pipe_sync_vm8() {
    asm volatile("" ::: "memory");
    __builtin_amdgcn_s_waitcnt(0xF78);
    __builtin_amdgcn_s_barrier();
    asm volatile("" ::: "memory");
}
__device__ __forceinline__ void pipe_sync_vm4() {
    asm volatile("" ::: "memory");
    __builtin_amdgcn_s_waitcnt(0xF74);
    __builtin_amdgcn_s_barrier();
    asm volatile("" ::: "memory");
}
__device__ __forceinline__ void pipe_sync_vm0() {
    asm volatile("" ::: "memory");
    __builtin_amdgcn_s_waitcnt(0xF70);
    __builtin_amdgcn_s_barrier();
    asm volatile("" ::: "memory");
}

// ---------------- x fp32 -> bf16 ----------------
__global__ void xconv_k(const float* __restrict__ x, __bf16* __restrict__ xb) {
    int i = (blockIdx.x * 256 + threadIdx.x) * 4;
    float4 v = *(const float4*)(x + i);
    bf16x4 o;
    o[0] = (__bf16)v.x; o[1] = (__bf16)v.y; o[2] = (__bf16)v.z; o[3] = (__bf16)v.w;
    *(bf16x4*)(xb + i) = o;
}

// ---------------- weight transpose+convert: [E][K][N] fp32 -> [E][N][K] bf16 ----------------
__global__ __launch_bounds__(256) void wtrans_k(const float* __restrict__ in0,
                                                const float* __restrict__ in1,
                                                __bf16* __restrict__ out0,
                                                __bf16* __restrict__ out1,
                                                int K, int N) {
    const int z = blockIdx.z;
    const int e = z & 7;
    const float* in  = (z >> 3) ? in1  : in0;
    __bf16*     out  = (z >> 3) ? out1 : out0;
    const int k0 = blockIdx.x * 64, n0 = blockIdx.y * 64;
    __shared__ float sT[64 * 65];
    const float* ip = in + (size_t)e * K * N;
    const int t = threadIdx.x;
    const int kl = t >> 4;            // 0..15
    const int n4 = (t & 15) * 4;
#pragma unroll
    for (int j = 0; j < 4; ++j) {
        int k = kl + j * 16;
        float4 v = *(const float4*)(ip + (size_t)(k0 + k) * N + n0 + n4);
        sT[(n4 + 0) * 65 + k] = v.x;
        sT[(n4 + 1) * 65 + k] = v.y;
        sT[(n4 + 2) * 65 + k] = v.z;
        sT[(n4 + 3) * 65 + k] = v.w;
    }
    __syncthreads();
    const int n = t >> 2;             // 0..63
    const int kc = (t & 3) * 16;
    bf16x8 o0, o1;
#pragma unroll
    for (int j = 0; j < 8; ++j) {
        o0[j] = (__bf16)sT[n * 65 + kc + j];
        o1[j] = (__bf16)sT[n * 65 + kc + 8 + j];
    }
    __bf16* op = out + (size_t)e * N * K + (size_t)(n0 + n) * K + k0 + kc;
    *(bf16x8*)op = o0;
    *(bf16x8*)(op + 8) = o1;
}

// ---------------- router ----------------
__global__ __launch_bounds__(256) void router_k(const float* __restrict__ x,
                                                const float* __restrict__ wgate,
                                                int* __restrict__ counts,
                                                int* __restrict__ tok_list,
                                                float* __restrict__ wgt) {
    const int t = blockIdx.x;
    const int tid = threadIdx.x;
    float acc[NEXP];
#pragma unroll
    for (int e = 0; e < NEXP; ++e) acc[e] = 0.f;
    const float* xr = x + (size_t)t * H_DIM;
    for (int k = tid; k < H_DIM; k += 256) {
        float xv = xr[k];
#pragma unroll
        for (int e = 0; e < NEXP; ++e) acc[e] += xv * wgate[e * H_DIM + k];
    }
    __shared__ float s_red[NEXP][4];
    __shared__ float s_logit[NEXP];
    const int lane = tid & 63, w = tid >> 6;
#pragma unroll
    for (int e = 0; e < NEXP; ++e) {
        float v = acc[e];
#pragma unroll
        for (int off = 32; off > 0; off >>= 1) v += __shfl_down(v, off, 64);
        if (lane == 0) s_red[e][w] = v;
    }
    __syncthreads();
    if (tid < NEXP) s_logit[tid] = s_red[tid][0] + s_red[tid][1] + s_red[tid][2] + s_red[tid][3];
    __syncthreads();
    if (tid == 0) {
        int i0 = 0; float l0 = s_logit[0];
        for (int e = 1; e < NEXP; ++e) if (s_logit[e] > l0) { l0 = s_logit[e]; i0 = e; }
        int i1 = -1; float l1 = -1e30f;
        for (int e = 0; e < NEXP; ++e) if (e != i0 && s_logit[e] > l1) { l1 = s_logit[e]; i1 = e; }
        float w0 = 1.f / (1.f + expf(l1 - l0));
        float w1 = 1.f - w0;
        int p0 = atomicAdd(&counts[i0], 1);
        tok_list[i0 * TTOK + p0] = t; wgt[i0 * TTOK + p0] = w0;
        int p1 = atomicAdd(&counts[i1], 1);
        tok_list[i1 * TTOK + p1] = t; wgt[i1 * TTOK + p1] = w1;
    }
}

// ---------------- GEMM1: h = silu(x@Wg)*(x@Wu); BM=128, BN=64(G)+64(U), BK=32 ----------------
// 4-stage pipeline, depth-3 prefetch, vmcnt(8) steady-state (4 gl2l/wave/tile).
// Grid: x = e*12+nt (96, %8==0 -> stripe pins to one XCD), y = m-tile.
__global__ __launch_bounds__(256, 2) void gemm1_k(
    const __bf16* __restrict__ xb, const __bf16* __restrict__ Wgt,
    const __bf16* __restrict__ Wut, const int* __restrict__ counts,
    const int* __restrict__ tok_list, __bf16* __restrict__ hbuf) {
    const int g = blockIdx.x;
    const int e = g / 12, nt = g % 12;
    const int cnt = counts[e];
    const int m0 = blockIdx.y * 128;
    if (m0 >= cnt) return;
    const int tid = threadIdx.x;
    const int lane = tid & 63, w = tid >> 6;

    __shared__ __bf16 sA[4][128 * 32];
    __shared__ __bf16 sG[4][64 * 32];
    __shared__ __bf16 sU[4][64 * 32];
    __shared__ int s_tok[128];
    __shared__ int s_off;

    if (tid == 0) { int o = 0; for (int j = 0; j < e; ++j) o += counts[j]; s_off = o; }
    if (tid < 128) {
        int m = m0 + tid;
        s_tok[tid] = tok_list[e * TTOK + (m < cnt ? m : cnt - 1)];
    }
    __syncthreads();
    const int off = s_off;

    // staging: rows of 32 k-elems = 4 chunks of 16B; logical chunk c of row r at slot c^(r&3)
    const int srow = lane >> 2;                    // 0..15 within a 16-row group
    const int gof = ((lane & 3) ^ (srow & 3)) * 8; // logical chunk offset this lane stages
    const __bf16* pA[2]; int lofA[2];
#pragma unroll
    for (int i = 0; i < 2; ++i) {
        int r = i * 64 + w * 16 + srow;
        pA[i] = xb + (size_t)s_tok[r] * H_DIM + gof;
        lofA[i] = (i * 64 + w * 16) * 32;
    }
    const __bf16 *pG, *pU;
    const int lofGU = (w * 16) * 32;
    {
        int r = w * 16 + srow;
        size_t grow = (size_t)e * I_DIM + nt * 64 + r;
        pG = Wgt + grow * H_DIM + gof;
        pU = Wut + grow * H_DIM + gof;
    }

    const int wm = w & 1, wn = w >> 1;
    const int l15 = lane & 15, kq = lane >> 4;
    const int swz = (kq ^ (l15 & 3)) * 8;          // fragment k-chunk slot

    f32x4 accG[4][2], accU[4][2];
#pragma unroll
    for (int mf = 0; mf < 4; ++mf)
#pragma unroll
        for (int nf = 0; nf < 2; ++nf) {
            accG[mf][nf] = (f32x4){0.f, 0.f, 0.f, 0.f};
            accU[mf][nf] = (f32x4){0.f, 0.f, 0.f, 0.f};
        }

#define G1_ISSUE(T, BUF)                                             \
    {                                                                \
        const int kb_ = (T) * 32;                                    \
        gl2l(pA[0] + kb_, &sA[BUF][lofA[0]]);                        \
        gl2l(pA[1] + kb_, &sA[BUF][lofA[1]]);                        \
        gl2l(pG + kb_, &sG[BUF][lofGU]);                             \
        gl2l(pU + kb_, &sU[BUF][lofGU]);                             \
    }

#define G1_COMPUTE(P)                                                                    \
    {                                                                                    \
        bf16x8 af[4], bg[2], bu[2];                                                      \
        _Pragma("unroll")                                                                \
        for (int mf = 0; mf < 4; ++mf)                                                   \
            af[mf] = *(const bf16x8*)(&sA[P][0] + (wm * 64 + mf * 16 + l15) * 32 + swz); \
        _Pragma("unroll")                                                                \
        for (int nf = 0; nf < 2; ++nf) {                                                 \
            bg[nf] = *(const bf16x8*)(&sG[P][0] + (wn * 32 + nf * 16 + l15) * 32 + swz); \
            bu[nf] = *(const bf16x8*)(&sU[P][0] + (wn * 32 + nf * 16 + l15) * 32 + swz); \
        }                                                                                \
        _Pragma("unroll")                                                                \
        for (int mf = 0; mf < 4; ++mf)                                                   \
            _Pragma("unroll")                                                            \
            for (int nf = 0; nf < 2; ++nf) {                                             \
                accG[mf][nf] = __builtin_amdgcn_mfma_f32_16x16x32_bf16(af[mf], bg[nf], accG[mf][nf], 0, 0, 0); \
                accU[mf][nf] = __builtin_amdgcn_mfma_f32_16x16x32_bf16(af[mf], bu[nf], accU[mf][nf], 0, 0, 0); \
            }                                                                            \
    }

    // prefetch tiles 0,1,2 (12 loads/wave in flight)
    G1_ISSUE(0, 0); G1_ISSUE(1, 1); G1_ISSUE(2, 2);

    // steady: 64 tiles total; iters 0..59 issue tiles 3..62
#pragma unroll 4
    for (int it = 0; it < 60; ++it) {
        const int p = it & 3;
        pipe_sync_vm8();                 // tile `it` landed; it+1,it+2 in flight
        G1_ISSUE(it + 3, (it + 3) & 3);
        G1_COMPUTE(p);
    }
    pipe_sync_vm8(); G1_ISSUE(63, 3); G1_COMPUTE(0);   // it=60
    pipe_sync_vm8(); G1_COMPUTE(1);                    // it=61
    pipe_sync_vm4(); G1_COMPUTE(2);                    // it=62
    pipe_sync_vm0(); G1_COMPUTE(3);                    // it=63
#undef G1_ISSUE
#undef G1_COMPUTE

    // epilogue: silu(g)*u -> bf16 (C layout: col=lane&15, row=(lane>>4)*4+reg)
#pragma unroll
    for (int mf = 0; mf < 4; ++mf) {
#pragma unroll
        for (int reg = 0; reg < 4; ++reg) {
            int m = m0 + wm * 64 + mf * 16 + kq * 4 + reg;
            if (m < cnt) {
                size_t rowbase = (size_t)(off + m) * I_DIM;
#pragma unroll
                for (int nf = 0; nf < 2; ++nf) {
                    float g1 = accG[mf][nf][reg], u1 = accU[mf][nf][reg];
                    float h = (g1 / (1.f + __expf(-g1))) * u1;
                    hbuf[rowbase + nt * 64 + wn * 32 + nf * 16 + l15] = (__bf16)h;
                }
            }
        }
    }
}

// ---------------- GEMM2: y = h @ Wd_t, scatter-add w*y; BM=128, BN=128, BK=32 ----------------
// same 4-stage pipeline; grid x = e*16+nt (128), y = m-tile.
__global__ __launch_bounds__(256, 2) void gemm2_k(
    const __bf16* __restrict__ hbuf, const __bf16* __restrict__ Wdt,
    const int* __restrict__ counts, const int* __restrict__ tok_list,
    const float* __restrict__ wgt, float* __restrict__ out) {
    const int g = blockIdx.x;
    const int e = g >> 4, nt = g & 15;
    const int cnt = counts[e];
    const int m0 = blockIdx.y * 128;
    if (m0 >= cnt) return;
    const int tid = threadIdx.x;
    const int lane = tid & 63, w = tid >> 6;

    __shared__ __bf16 sA[4][128 * 32];
    __shared__ __bf16 sB[4][128 * 32];
    __shared__ int s_tok[128];
    __shared__ float s_w[128];
    __shared__ int s_off;

    if (tid == 0) { int o = 0; for (int j = 0; j < e; ++j) o += counts[j]; s_off = o; }
    if (tid < 128) {
        int m = m0 + tid;
        if (m < cnt) { s_tok[tid] = tok_list[e * TTOK + m]; s_w[tid] = wgt[e * TTOK + m]; }
        else         { s_tok[tid] = 0;                      s_w[tid] = 0.f; }
    }
    __syncthreads();
    const int off = s_off;

    const int srow = lane >> 2;
    const int gof = ((lane & 3) ^ (srow & 3)) * 8;
    const __bf16* pA[2]; int lofA[2];
    const __bf16* pB[2]; int lofB[2];
#pragma unroll
    for (int i = 0; i < 2; ++i) {
        int r = i * 64 + w * 16 + srow;
        pA[i] = hbuf + (size_t)(off + m0 + r) * I_DIM + gof;
        pB[i] = Wdt + ((size_t)e * H_DIM + nt * 128 + r) * I_DIM + gof;
        lofA[i] = (i * 64 + w * 16) * 32;
        lofB[i] = (i * 64 + w * 16) * 32;
    }

    const int wm = w & 1, wn = w >> 1;
    const int l15 = lane & 15, kq = lane >> 4;
    const int swz = (kq ^ (l15 & 3)) * 8;

    f32x4 acc[4][4];
#pragma unroll
    for (int mf = 0; mf < 4; ++mf)
#pragma unroll
        for (int nf = 0; nf < 4; ++nf) acc[mf][nf] = (f32x4){0.f, 0.f, 0.f, 0.f};

#define G2_ISSUE(T, BUF)                                             \
    {                                                                \
        const int kb_ = (T) * 32;                                    \
        gl2l(pA[0] + kb_, &sA[BUF][lofA[0]]);                        \
        gl2l(pA[1] + kb_, &sA[BUF][lofA[1]]);                        \
        gl2l(pB[0] + kb_, &sB[BUF][lofB[0]]);                        \
        gl2l(pB[1] + kb_, &sB[BUF][lofB[1]]);                        \
    }

#define G2_COMPUTE(P)                                                                    \
    {                                                                                    \
        bf16x8 af[4], bb[4];                                                             \
        _Pragma("unroll")                                                                \
        for (int mf = 0; mf < 4; ++mf)                                                   \
            af[mf] = *(const bf16x8*)(&sA[P][0] + (wm * 64 + mf * 16 + l15) * 32 + swz); \
        _Pragma("unroll")                                                                \
        for (int nf = 0; nf < 4; ++nf)                                                   \
            bb[nf] = *(const bf16x8*)(&sB[P][0] + (wn * 64 + nf * 16 + l15) * 32 + swz); \
        _Pragma("unroll")                                                                \
        for (int mf = 0; mf < 4; ++mf)                                                   \
            _Pragma("unroll")                                                            \
            for (int nf = 0; nf < 4; ++nf)                                               \
                acc[mf][nf] = __builtin_amdgcn_mfma_f32_16x16x32_bf16(af[mf], bb[nf], acc[mf][nf], 0, 0, 0); \
    }

    // 24 tiles; prefetch 0,1,2; iters 0..19 issue tiles 3..22
    G2_ISSUE(0, 0); G2_ISSUE(1, 1); G2_ISSUE(2, 2);
#pragma unroll 4
    for (int it = 0; it < 20; ++it) {
        const int p = it & 3;
        pipe_sync_vm8();
        G2_ISSUE(it + 3, (it + 3) & 3);
        G2_COMPUTE(p);
    }
    pipe_sync_vm8(); G2_ISSUE(23, 3); G2_COMPUTE(0);   // it=20
    pipe_sync_vm8(); G2_COMPUTE(1);                    // it=21
    pipe_sync_vm4(); G2_COMPUTE(2);                    // it=22
    pipe_sync_vm0(); G2_COMPUTE(3);                    // it=23
#undef G2_ISSUE
#undef G2_COMPUTE

#pragma unroll
    for (int mf = 0; mf < 4; ++mf) {
#pragma unroll
        for (int reg = 0; reg < 4; ++reg) {
            int m_loc = wm * 64 + mf * 16 + kq * 4 + reg;
            if (m0 + m_loc < cnt) {
                int tok = s_tok[m_loc];
                float wv = s_w[m_loc];
                float* orow = out + (size_t)tok * H_DIM + nt * 128 + wn * 64 + l15;
#pragma unroll
                for (int nf = 0; nf < 4; ++nf)
                    atomicAdd(orow + nf * 16, wv * acc[mf][nf][reg]);
            }
        }
    }
}

extern "C" void kernel_launch(void* const* d_in, const int* in_sizes, int n_in,
                              void* d_out, int out_size, void* d_ws, size_t ws_size,
                              hipStream_t stream) {
    const float* x     = (const float*)d_in[0];
    const float* Wgate = (const float*)d_in[1];
    const float* Wg    = (const float*)d_in[2];
    const float* Wu    = (const float*)d_in[3];
    const float* Wd    = (const float*)d_in[4];
    float* out = (float*)d_out;
    char* ws = (char*)d_ws;

    int*    counts   = (int*)(ws + WS_COUNTS);
    int*    tok_list = (int*)(ws + WS_TOK);
    float*  wgt      = (float*)(ws + WS_WGTW);
    __bf16* xb       = (__bf16*)(ws + WS_XBF);
    __bf16* hbuf     = (__bf16*)(ws + WS_HBUF);
    __bf16* Wg_t     = (__bf16*)(ws + WS_WG_T);
    __bf16* Wu_t     = (__bf16*)(ws + WS_WU_T);
    __bf16* Wd_t     = (__bf16*)(ws + WS_WD_T);

    hipMemsetAsync(counts, 0, 32, stream);
    hipMemsetAsync(d_out, 0, (size_t)TTOK * H_DIM * sizeof(float), stream);

    xconv_k<<<(TTOK * H_DIM / 4) / 256, 256, 0, stream>>>(x, xb);
    router_k<<<TTOK, 256, 0, stream>>>(x, Wgate, counts, tok_list, wgt);
    // Wg,Wu: [E][2048][768] -> [E][768][2048] ; Wd: [E][768][2048] -> [E][2048][768]
    wtrans_k<<<dim3(H_DIM / 64, I_DIM / 64, 2 * NEXP), 256, 0, stream>>>(Wg, Wu, Wg_t, Wu_t, H_DIM, I_DIM);
    wtrans_k<<<dim3(I_DIM / 64, H_DIM / 64, NEXP), 256, 0, stream>>>(Wd, Wd, Wd_t, Wd_t, I_DIM, H_DIM);
    gemm1_k<<<dim3(96, 16), 256, 0, stream>>>(xb, Wg_t, Wu_t, counts, tok_list, hbuf);
    gemm2_k<<<dim3(128, 16), 256, 0, stream>>>(hbuf, Wd_t, counts, tok_list, wgt, out);
}